// Round 1
// baseline (13.320 us; speedup 1.0000x reference)
//
#include <hip/hip_runtime.h>

#define NUM_PAGES 1048576
#define TPP 32
#define SLOTS 256
#define MPPS 4096

// ---------------------------------------------------------------------------
// Kernel 1: bulk copy page_status and page_map into the output (int4 vectorized)
// ---------------------------------------------------------------------------
__global__ __launch_bounds__(256) void copy_kernel(
    const int4* __restrict__ ps, const int4* __restrict__ pm,
    int4* __restrict__ out_ps, int4* __restrict__ out_pm, int n4)
{
    int i = blockIdx.x * blockDim.x + threadIdx.x;
    int stride = gridDim.x * blockDim.x;
    for (; i < n4; i += stride) {
        out_ps[i] = ps[i];
        out_pm[i] = pm[i];
    }
}

// ---------------------------------------------------------------------------
// Kernel 2: single-block allocator logic
// ---------------------------------------------------------------------------
__global__ __launch_bounds__(1024) void logic_kernel(
    const int* __restrict__ ps,      // page_status (input, unmodified)
    const int* __restrict__ seq,     // sequence_lengths
    const int* __restrict__ npu,     // num_pages_used
    const int* __restrict__ cp,      // current_page
    int* __restrict__ out_ps,        // copied page_status (already written by copy_kernel)
    int* __restrict__ out_pm,        // copied page_map
    int* __restrict__ out_seq,
    int* __restrict__ out_npu,
    int* __restrict__ out_cp,
    int* __restrict__ out_cpp)
{
    __shared__ int s_need_slot[SLOTS];  // compacted list of slots needing a page
    __shared__ int s_free[SLOTS];       // ascending free-page indices
    __shared__ int s_scan[16];          // per-wave counts / offsets
    __shared__ int s_K;
    __shared__ int s_cursor;

    const int t    = threadIdx.x;
    const int lane = t & 63;
    const int wave = t >> 6;
    const unsigned long long mask_lt = (1ULL << lane) - 1ULL;

    // ---- Phase 1: per-slot math + needs flag -------------------------------
    int needs = 0;
    if (t < SLOTS) {
        int s  = seq[t];
        int c  = cp[t];
        int ns = s + ((c == -1) ? 0 : 1);
        int nn = (ns + TPP - 1) / TPP;
        int nc = (ns == 0) ? 0 : ((ns - 1) % TPP);
        out_seq[t] = ns;
        out_npu[t] = nn;
        out_cpp[t] = nc;
        out_cp[t]  = c;                 // provisional; overwritten if allocated
        needs = (nn > npu[t]) ? 1 : 0;
    }
    unsigned long long b = __ballot(needs);
    int rank   = __popcll(b & mask_lt);
    int wcount = __popcll(b);
    if (lane == 0) s_scan[wave] = wcount;
    __syncthreads();
    if (t == 0) {
        int acc = 0;
        for (int w = 0; w < 16; ++w) { int c = s_scan[w]; s_scan[w] = acc; acc += c; }
        s_K = acc;
        s_cursor = 0;
    }
    __syncthreads();
    if (needs) s_need_slot[s_scan[wave] + rank] = t;
    const int K = s_K;
    __syncthreads();

    // ---- Phase 2: find first K free pages in page_status[1:] (ascending) ---
    for (int base = 1; base < NUM_PAGES && s_cursor < K; base += 1024) {
        int idx    = base + t;
        int isfree = (idx < NUM_PAGES && ps[idx] == 0) ? 1 : 0;
        unsigned long long fb = __ballot(isfree);
        int frank = __popcll(fb & mask_lt);
        int fcnt  = __popcll(fb);
        if (lane == 0) s_scan[wave] = fcnt;
        __syncthreads();
        if (t == 0) {
            int acc = s_cursor;
            for (int w = 0; w < 16; ++w) { int c = s_scan[w]; s_scan[w] = acc; acc += c; }
            s_cursor = acc;
        }
        __syncthreads();
        if (isfree) {
            int pos = s_scan[wave] + frank;
            if (pos < K) s_free[pos] = idx;
        }
        __syncthreads();
    }
    // fallback: no free page found -> reference yields index 0
    if (t < K && t >= s_cursor) s_free[t] = 0;
    __syncthreads();

    // ---- Phase 3: apply the K allocations ----------------------------------
    if (t < K) {
        int slot = s_need_slot[t];
        int nfp  = s_free[t];
        out_ps[nfp] = 1;
        out_pm[slot * MPPS + npu[slot]] = nfp;
        out_cp[slot] = nfp;
    }
}

// ---------------------------------------------------------------------------
extern "C" void kernel_launch(void* const* d_in, const int* in_sizes, int n_in,
                              void* d_out, int out_size, void* d_ws, size_t ws_size,
                              hipStream_t stream)
{
    const int* page_status = (const int*)d_in[0];
    const int* page_map    = (const int*)d_in[1];
    const int* seq         = (const int*)d_in[2];
    const int* npu         = (const int*)d_in[3];
    const int* cp          = (const int*)d_in[4];
    // d_in[5] (current_page_position) is unused by the reference update.

    int* out     = (int*)d_out;
    int* out_ps  = out;                       // NUM_PAGES
    int* out_pm  = out + NUM_PAGES;           // SLOTS*MPPS == NUM_PAGES
    int* out_seq = out + 2 * NUM_PAGES;       // SLOTS
    int* out_npu = out_seq + SLOTS;
    int* out_cp  = out_npu + SLOTS;
    int* out_cpp = out_cp + SLOTS;

    const int n4 = NUM_PAGES / 4;             // 262144 int4 per array
    copy_kernel<<<1024, 256, 0, stream>>>(
        (const int4*)page_status, (const int4*)page_map,
        (int4*)out_ps, (int4*)out_pm, n4);

    logic_kernel<<<1, 1024, 0, stream>>>(
        page_status, seq, npu, cp,
        out_ps, out_pm, out_seq, out_npu, out_cp, out_cpp);
}